// Round 8
// baseline (920.179 us; speedup 1.0000x reference)
//
#include <hip/hip_runtime.h>

#define E_EXP 4
#define D_MODEL 1024
#define B_BATCH 4
#define S_SEQ 4096
#define NTOK (B_BATCH*S_SEQ)   // 16384
#define CHUNK 16
#define NCHUNK (S_SEQ/CHUNK)   // 256

typedef float f4 __attribute__((ext_vector_type(4)));
typedef float f32x4 __attribute__((ext_vector_type(4)));
typedef short bf16x8 __attribute__((ext_vector_type(8)));

__device__ __forceinline__ unsigned short f2b(float f){
  union{float f;unsigned u;}v; v.f=f;
  unsigned r = v.u + 0x7fffu + ((v.u>>16)&1u);
  return (unsigned short)(r>>16);
}
__device__ __forceinline__ float b2f_lo(unsigned v){ union{unsigned u;float f;}x; x.u=v<<16; return x.f; }
__device__ __forceinline__ float b2f_hi(unsigned v){ union{unsigned u;float f;}x; x.u=v&0xffff0000u; return x.f; }

__device__ __forceinline__ void gload_lds16(const void* g, void* l){
  __builtin_amdgcn_global_load_lds(
      (const __attribute__((address_space(1))) void*)g,
      (__attribute__((address_space(3))) void*)l, 16, 0, 0);
}

// ---------------- fused prep: x -> bf16 AND router top-2 softmax (reads x ONCE) ----
__global__ __launch_bounds__(256) void prep(
    const float* __restrict__ x, const float* __restrict__ Wgate,
    unsigned short* __restrict__ xbf, float* __restrict__ wtok)
{
  int tok  = blockIdx.x*4 + (threadIdx.x>>6);
  int lane = threadIdx.x & 63;
  const float* xr = x + (size_t)tok*D_MODEL;
  unsigned short* xb = xbf + (size_t)tok*D_MODEL;
  float acc0=0.f,acc1=0.f,acc2=0.f,acc3=0.f;
  #pragma unroll
  for (int j=0;j<4;j++){
    int k = lane*4 + j*256;
    f4 v  = *(const f4*)(xr + k);
    f4 w0 = *(const f4*)(Wgate + 0*D_MODEL + k);
    f4 w1 = *(const f4*)(Wgate + 1*D_MODEL + k);
    f4 w2 = *(const f4*)(Wgate + 2*D_MODEL + k);
    f4 w3 = *(const f4*)(Wgate + 3*D_MODEL + k);
    #pragma unroll
    for (int q=0;q<4;q++){
      acc0 += v[q]*w0[q];
      acc1 += v[q]*w1[q];
      acc2 += v[q]*w2[q];
      acc3 += v[q]*w3[q];
    }
    ushort4 o; o.x=f2b(v[0]); o.y=f2b(v[1]); o.z=f2b(v[2]); o.w=f2b(v[3]);
    *(ushort4*)(xb + k) = o;
  }
  #pragma unroll
  for (int off=32;off>0;off>>=1){
    acc0 += __shfl_down(acc0,off);
    acc1 += __shfl_down(acc1,off);
    acc2 += __shfl_down(acc2,off);
    acc3 += __shfl_down(acc3,off);
  }
  if (lane==0){
    float l[4]={acc0,acc1,acc2,acc3};
    int i1=0;
    #pragma unroll
    for(int e=1;e<4;e++) if (l[e]>l[i1]) i1=e;
    int i2=-1;
    #pragma unroll
    for(int e=0;e<4;e++){ if(e==i1) continue; if(i2<0||l[e]>l[i2]) i2=e; }
    float ex = __expf(l[i2]-l[i1]);
    float w1 = 1.f/(1.f+ex);
    float w2 = ex/(1.f+ex);
    float w[4]={0.f,0.f,0.f,0.f};
    w[i1]=w1; w[i2]=w2;
    float* wp = wtok + (size_t)tok*E_EXP;
    wp[0]=w[0]; wp[1]=w[1]; wp[2]=w[2]; wp[3]=w[3];
  }
}

// Wg/Wv/Wd expert slices -> Wcat[le][3][D][D] bf16
__global__ __launch_bounds__(256) void cvt_w3(const float* __restrict__ Wg,
                                              const float* __restrict__ Wv,
                                              const float* __restrict__ Wd,
                                              unsigned short* __restrict__ Wcat,
                                              int e0)
{
  const size_t DD = (size_t)D_MODEL*D_MODEL;   // 2^20
  size_t i4 = ((size_t)blockIdx.x*256 + threadIdx.x)*4;
  size_t le3m = i4 >> 20;          // / DD
  size_t rem  = i4 & (DD-1);
  int mat = (int)(le3m % 3);
  int le  = (int)(le3m / 3);
  const float* src = (mat==0 ? Wg : (mat==1 ? Wv : Wd)) + (size_t)(e0+le)*DD + rem;
  f4 v = *(const f4*)src;
  ushort4 o; o.x=f2b(v[0]); o.y=f2b(v[1]); o.z=f2b(v[2]); o.w=f2b(v[3]);
  *(ushort4*)(Wcat + le3m*DD + rem) = o;
}

// ---------------- 256x256 bf16 MFMA GEMM, 8-phase counted-vmcnt schedule ----------------
// (Round-1/6 verified kernel, best measured: ~230-237 us/dispatch, MfmaUtil 37-39%.)
#define BM2 256
#define BN2 256
#define BK2 64
#define NT2 (D_MODEL/BK2)   // 16

__global__ __launch_bounds__(512, 2) void gemm256(
    const unsigned short* __restrict__ A,     // xbf [NTOK][D]
    const unsigned short* __restrict__ Wcat,  // [G][3][D][D] bf16
    unsigned short* __restrict__ gvd)         // [G][3][NTOK][D] bf16 raw
{
  __shared__ unsigned short sA[2][BM2][BK2];  // 64 KiB
  __shared__ unsigned short sB[2][BN2][BK2];  // 64 KiB
  const size_t DD = (size_t)D_MODEL*D_MODEL;
  const size_t ND = (size_t)NTOK*D_MODEL;

  const int le    = blockIdx.z;
  const int mbase = blockIdx.x*BM2;
  const int ntile = blockIdx.y;              // 0..11
  const int mat   = ntile>>2;                // which matrix (g/v/d)
  const int nbase = (ntile&3)*BN2;           // col within matrix

  const int tid  = threadIdx.x;
  const int wave = tid>>6, lane = tid&63;
  const int wm = wave>>2, wn = wave&3;       // 2M x 4N wave grid; per-wave out 128x64
  const int l15 = lane&15;
  const int l8  = lane>>3;
  const int lc  = (lane&7) ^ l8;             // pre-swizzled logical chunk for staging

  const unsigned short* Wmat = Wcat + ((size_t)le*3 + mat)*DD;
  const unsigned short* gA = A + (size_t)(mbase + wave*8 + l8)*D_MODEL + lc*8;
  const int bBw = (wave>>1)*64 + (wave&1)*8; // per-wave B dest row base
  const unsigned short* gB = Wmat + (size_t)(nbase + bBw + l8)*D_MODEL + lc*8;

  // fragment read addressing (swizzle-aware)
  const int arow = wm*128 + l15;
  const int brow = wn*64  + l15;
  const int ach0 = (((lane>>4)    ) ^ (lane&7))*8;   // kk=0 phys chunk, ushort off
  const int ach1 = (((lane>>4) + 4) ^ (lane&7))*8;   // kk=1

  f32x4 acc[8][4];
  #pragma unroll
  for (int i=0;i<8;i++)
    #pragma unroll
    for (int j=0;j<4;j++) acc[i][j] = 0;

  bf16x8 af[4][2], bfv[2][2];

#define STAGE_A2(slot,t,mh) do{ \
  gload_lds16(gA + (size_t)((mh)*64)*D_MODEL     + (t)*BK2, &sA[slot][(mh)*64 + wave*8][0]); \
  gload_lds16(gA + (size_t)(128+(mh)*64)*D_MODEL + (t)*BK2, &sA[slot][128+(mh)*64 + wave*8][0]); \
}while(0)
#define STAGE_B2(slot,t,nh) do{ \
  gload_lds16(gB + (size_t)((nh)*32)*D_MODEL    + (t)*BK2, &sB[slot][bBw + (nh)*32][0]); \
  gload_lds16(gB + (size_t)((nh)*32+16)*D_MODEL + (t)*BK2, &sB[slot][bBw + (nh)*32 + 16][0]); \
}while(0)
#define LOAD_A2(slot,mh) do{ \
  _Pragma("unroll") for (int _m=0;_m<4;++_m){ \
    af[_m][0] = *(const bf16x8*)&sA[slot][arow + ((mh)*4+_m)*16][ach0]; \
    af[_m][1] = *(const bf16x8*)&sA[slot][arow + ((mh)*4+_m)*16][ach1]; \
  } \
}while(0)
#define LOAD_B2(slot,nh) do{ \
  _Pragma("unroll") for (int _n=0;_n<2;++_n){ \
    bfv[_n][0] = *(const bf16x8*)&sB[slot][brow + ((nh)*2+_n)*16][ach0]; \
    bfv[_n][1] = *(const bf16x8*)&sB[slot][brow + ((nh)*2+_n)*16][ach1]; \
  } \
}while(0)
#define MQ2(mh,nh) do{ \
  _Pragma("unroll") for (int _m=0;_m<4;++_m) \
  _Pragma("unroll") for (int _n=0;_n<2;++_n) \
  _Pragma("unroll") for (int _k=0;_k<2;++_k) \
    acc[(mh)*4+_m][(nh)*2+_n] = __builtin_amdgcn_mfma_f32_16x16x32_bf16( \
        af[_m][_k], bfv[_n][_k], acc[(mh)*4+_m][(nh)*2+_n], 0,0,0); \
}while(0)
#define KC_LGKM0  asm volatile("s_waitcnt lgkmcnt(0)" ::: "memory")
#define KC_LGKM8  asm volatile("s_waitcnt lgkmcnt(8)" ::: "memory")
#define KC_VM4    asm volatile("s_waitcnt vmcnt(4)" ::: "memory")
#define BAR       __builtin_amdgcn_s_barrier()
#define PRIO1     __builtin_amdgcn_s_setprio(1)
#define PRIO0     __builtin_amdgcn_s_setprio(0)

#define WINDOW2(slot,oslot,T1,T2) do{ \
  LOAD_A2(slot,0); LOAD_B2(slot,0); \
  STAGE_A2(oslot,T1,1); STAGE_B2(oslot,T1,0); \
  KC_LGKM8; BAR; KC_LGKM0; \
  PRIO1; MQ2(0,0); PRIO0; BAR; \
  LOAD_B2(slot,1); \
  BAR; KC_LGKM0; \
  PRIO1; MQ2(0,1); PRIO0; BAR; \
  LOAD_A2(slot,1); \
  STAGE_A2(slot,T2,0); \
  BAR; KC_LGKM0; \
  PRIO1; MQ2(1,1); PRIO0; BAR; \
  LOAD_B2(slot,0); \
  STAGE_B2(slot,T2,1); \
  KC_VM4; BAR; KC_LGKM0; \
  PRIO1; MQ2(1,0); PRIO0; BAR; \
}while(0)

  // prologue: tile 0 fully into slot0; A0+B1 of tile 1 into slot1 (left in flight)
  STAGE_A2(0,0,0); STAGE_A2(0,0,1); STAGE_B2(0,0,0); STAGE_B2(0,0,1);
  STAGE_A2(1,1,0); STAGE_B2(1,1,1);
  KC_VM4; BAR;

  for (int tp=0; tp<NT2/2; ++tp){
    int ta = 2*tp+1;                       // always < NT2
    int tb = 2*tp+2; if (tb>=NT2) tb -= NT2;   // wrapped stages are in-bounds junk
    int tc = 2*tp+3; if (tc>=NT2) tc -= NT2;
    WINDOW2(0,1,ta,tb);
    WINDOW2(1,0,tb,tc);
  }

  asm volatile("s_waitcnt vmcnt(0)" ::: "memory");   // drain tail junk stages before exit

  // epilogue: raw bf16 store (C/D layout col=lane&15, row=(lane>>4)*4+r)
  unsigned short* outp = gvd + ((size_t)le*3 + mat)*ND;
  const int me = mbase + wm*128;
  const int ne = nbase + wn*64;
  #pragma unroll
  for (int mi=0;mi<8;mi++){
    #pragma unroll
    for (int r=0;r<4;r++){
      int m = me + mi*16 + (lane>>4)*4 + r;
      size_t rowoff = (size_t)m*D_MODEL;
      #pragma unroll
      for (int ni=0;ni<4;ni++){
        int n = ne + ni*16 + l15;
        outp[rowoff+n] = f2b(acc[mi][ni][r]);
      }
    }
  }
}

// ---------------- pass 1: bias+activation + local chunk scan; writes xs,aa in place ----------------
// (Round-6 proven form; CHUNK=16 doubles chunk parallelism and halves serial chains.)
__global__ __launch_bounds__(512) void scan_pass1(
    unsigned short* __restrict__ gvd,   // [G][3][NTOK][D]; g-plane becomes xs, d-plane becomes aa
    const float* __restrict__ bg, const float* __restrict__ bv, const float* __restrict__ bd,
    float* __restrict__ P, float* __restrict__ U, int e0)
{
  const size_t ND = (size_t)NTOK*D_MODEL;
  int blk = blockIdx.x;
  int c  = blk % NCHUNK;
  int b  = (blk / NCHUNK) % B_BATCH;
  int le = blk / (NCHUNK*B_BATCH);
  int d0 = threadIdx.x*2;
  int e  = e0 + le;

  float bg0 = bg[(size_t)e*D_MODEL+d0], bg1 = bg[(size_t)e*D_MODEL+d0+1];
  float bv0 = bv[(size_t)e*D_MODEL+d0], bv1 = bv[(size_t)e*D_MODEL+d0+1];
  float bd0 = bd[(size_t)e*D_MODEL+d0], bd1 = bd[(size_t)e*D_MODEL+d0+1];

  unsigned short* gp = gvd + (size_t)le*3*ND;      // g plane (-> xs)
  size_t base = (((size_t)b)*S_SEQ + (size_t)c*CHUNK)*D_MODEL + d0;
  float h0=0.f,h1=0.f,p0=1.f,p1=1.f;
  for (int t=0;t<CHUNK;t++){
    unsigned gw = *(const unsigned*)(gp + base);
    unsigned vw = *(const unsigned*)(gp + ND + base);
    unsigned dw = *(const unsigned*)(gp + 2*ND + base);
    float g0 = b2f_lo(gw)+bg0, g1 = b2f_hi(gw)+bg1;
    float v0 = b2f_lo(vw)+bv0, v1 = b2f_hi(vw)+bv1;
    float dd0 = b2f_lo(dw)+bd0, dd1 = b2f_hi(dw)+bd1;
    float x0 = (1.f/(1.f+__expf(-g0))) * (1.f - 2.f/(__expf(2.f*v0)+1.f));
    float x1 = (1.f/(1.f+__expf(-g1))) * (1.f - 2.f/(__expf(2.f*v1)+1.f));
    float a0 = 0.001f + 0.998f/(1.f+__expf(-dd0));
    float a1 = 0.001f + 0.998f/(1.f+__expf(-dd1));
    h0 = a0*h0 + x0; h1 = a1*h1 + x1;
    p0 *= a0; p1 *= a1;
    unsigned xsw = (unsigned)f2b(x0) | ((unsigned)f2b(x1)<<16);
    unsigned aaw = (unsigned)f2b(a0) | ((unsigned)f2b(a1)<<16);
    *(unsigned*)(gp + base)        = xsw;   // xs over g-plane
    *(unsigned*)(gp + 2*ND + base) = aaw;   // aa over d-plane
    base += D_MODEL;
  }
  size_t sidx = (((size_t)(le*B_BATCH + b))*NCHUNK + c)*D_MODEL + d0;
  P[sidx]=p0; P[sidx+1]=p1;
  U[sidx]=h0; U[sidx+1]=h1;
}

// ---------------- pass 2: sequential combine over chunks -> Hinit per chunk ----------------
__global__ __launch_bounds__(256) void scan_pass2(
    const float* __restrict__ P, const float* __restrict__ U, float* __restrict__ Hinit)
{
  int ch = blockIdx.x*256 + threadIdx.x;
  int d  = ch & (D_MODEL-1);
  int eb = ch >> 10;
  size_t base = (size_t)eb*NCHUNK*D_MODEL + d;
  float H=0.f;
  for (int c=0;c<NCHUNK;c++){
    size_t idx = base + (size_t)c*D_MODEL;
    Hinit[idx] = H;
    H = P[idx]*H + U[idx];
  }
}

// ---------------- pass 3: re-scan + fused top-2 weighted combine ----------------
template<int G, int FIRST>
__global__ __launch_bounds__(512) void scan_pass3(
    const unsigned short* __restrict__ gvd,   // xs = plane le*3, aa = plane le*3+2
    const float* __restrict__ Hinit, const float* __restrict__ wtok,
    float* __restrict__ out, int e0)
{
  const size_t ND = (size_t)NTOK*D_MODEL;
  int blk = blockIdx.x;
  int c = blk % NCHUNK;
  int b = blk / NCHUNK;
  int d0 = threadIdx.x*2;
  float h[G][2];
  #pragma unroll
  for (int le=0; le<G; le++){
    size_t hi = (((size_t)(le*B_BATCH+b))*NCHUNK + c)*D_MODEL + d0;
    h[le][0]=Hinit[hi]; h[le][1]=Hinit[hi+1];
  }
  int s0 = c*CHUNK;
  for (int t=0;t<CHUNK;t++){
    size_t n = (size_t)b*S_SEQ + s0 + t;
    float o0=0.f, o1=0.f;
    #pragma unroll
    for (int le=0;le<G;le++){
      float w = wtok[n*E_EXP + e0 + le];
      size_t idx = (size_t)le*3*ND + n*D_MODEL + d0;
      unsigned xv = *(const unsigned*)(gvd + idx);
      unsigned av = *(const unsigned*)(gvd + 2*ND + idx);
      h[le][0] = b2f_lo(av)*h[le][0] + b2f_lo(xv);
      h[le][1] = b2f_hi(av)*h[le][1] + b2f_hi(xv);
      o0 += w*h[le][0];
      o1 += w*h[le][1];
    }
    float* op = out + n*D_MODEL + d0;
    if (FIRST){ op[0]=o0;  op[1]=o1;  }
    else      { op[0]+=o0; op[1]+=o1; }
  }
}

extern "C" void kernel_launch(void* const* d_in, const int* in_sizes, int n_in,
                              void* d_out, int out_size, void* d_ws, size_t ws_size,
                              hipStream_t stream)
{
  const float* x     = (const float*)d_in[0];
  const float* Wg    = (const float*)d_in[1];
  const float* bg    = (const float*)d_in[2];
  const float* Wv    = (const float*)d_in[3];
  const float* bv    = (const float*)d_in[4];
  const float* Wd    = (const float*)d_in[5];
  const float* bd    = (const float*)d_in[6];
  const float* Wgate = (const float*)d_in[7];
  float* out = (float*)d_out;

  const size_t DD        = (size_t)D_MODEL*D_MODEL;
  const size_t ND        = (size_t)NTOK*D_MODEL;
  const size_t wtok_b    = (size_t)NTOK*E_EXP*4;             // 256 KiB
  const size_t xbf_b     = ND*2;                             // 32 MiB
  const size_t w_per_e   = 3*DD*2;                           // 6 MiB
  const size_t gvd_per_e = 3*ND*2;                           // 96 MiB
  const size_t st_per_e  = (size_t)B_BATCH*NCHUNK*D_MODEL*4; // 4 MiB (CHUNK=16)

  int G = 1;
  for (int g = 4; g >= 1; g >>= 1){
    size_t need = wtok_b + xbf_b + (size_t)g*(w_per_e + gvd_per_e + 3*st_per_e);
    if (need <= ws_size){ G = g; break; }
  }

  char* wsb = (char*)d_ws;
  size_t off = 0;
  float*          wtok = (float*)(wsb+off);          off += wtok_b;
  unsigned short* xbf  = (unsigned short*)(wsb+off); off += xbf_b;
  unsigned short* Wcat = (unsigned short*)(wsb+off); off += (size_t)G*w_per_e;
  unsigned short* gvd  = (unsigned short*)(wsb+off); off += (size_t)G*gvd_per_e;
  float*          P    = (float*)(wsb+off);          off += (size_t)G*st_per_e;
  float*          U    = (float*)(wsb+off);          off += (size_t)G*st_per_e;
  float*          Hi   = (float*)(wsb+off);

  prep<<<NTOK/4, 256, 0, stream>>>(x, Wgate, xbf, wtok);

  for (int e0=0; e0<E_EXP; e0+=G){
    cvt_w3<<<(unsigned)((size_t)G*3*DD/1024), 256, 0, stream>>>(Wg, Wv, Wd, Wcat, e0);

    dim3 gg(NTOK/BM2, 3*D_MODEL/BN2, G);
    gemm256<<<gg, 512, 0, stream>>>(xbf, Wcat, gvd);

    scan_pass1<<<G*B_BATCH*NCHUNK, 512, 0, stream>>>(gvd, bg, bv, bd, P, U, e0);
    scan_pass2<<<G*B_BATCH*D_MODEL/256, 256, 0, stream>>>(P, U, Hi);
    bool first = (e0 == 0);
    if (G==4)      scan_pass3<4,1><<<B_BATCH*NCHUNK, 512, 0, stream>>>(gvd, Hi, wtok, out, e0);
    else if (G==2){
      if (first) scan_pass3<2,1><<<B_BATCH*NCHUNK, 512, 0, stream>>>(gvd, Hi, wtok, out, e0);
      else       scan_pass3<2,0><<<B_BATCH*NCHUNK, 512, 0, stream>>>(gvd, Hi, wtok, out, e0);
    } else {
      if (first) scan_pass3<1,1><<<B_BATCH*NCHUNK, 512, 0, stream>>>(gvd, Hi, wtok, out, e0);
      else       scan_pass3<1,0><<<B_BATCH*NCHUNK, 512, 0, stream>>>(gvd, Hi, wtok, out, e0);
    }
  }
}

// Round 9
// 848.073 us; speedup vs baseline: 1.0850x; 1.0850x over previous
//
#include <hip/hip_runtime.h>

#define E_EXP 4
#define D_MODEL 1024
#define B_BATCH 4
#define S_SEQ 4096
#define NTOK (B_BATCH*S_SEQ)   // 16384
#define CHUNK 32
#define NCHUNK (S_SEQ/CHUNK)   // 128

typedef float f4 __attribute__((ext_vector_type(4)));
typedef float f32x4 __attribute__((ext_vector_type(4)));
typedef short bf16x8 __attribute__((ext_vector_type(8)));

__device__ __forceinline__ unsigned short f2b(float f){
  union{float f;unsigned u;}v; v.f=f;
  unsigned r = v.u + 0x7fffu + ((v.u>>16)&1u);
  return (unsigned short)(r>>16);
}
__device__ __forceinline__ float b2f_lo(unsigned v){ union{unsigned u;float f;}x; x.u=v<<16; return x.f; }
__device__ __forceinline__ float b2f_hi(unsigned v){ union{unsigned u;float f;}x; x.u=v&0xffff0000u; return x.f; }

__device__ __forceinline__ void gload_lds16(const void* g, void* l){
  __builtin_amdgcn_global_load_lds(
      (const __attribute__((address_space(1))) void*)g,
      (__attribute__((address_space(3))) void*)l, 16, 0, 0);
}

// ---------------- fused prep: x -> bf16 AND router top-2 softmax (reads x ONCE) ----
__global__ __launch_bounds__(256) void prep(
    const float* __restrict__ x, const float* __restrict__ Wgate,
    unsigned short* __restrict__ xbf, float* __restrict__ wtok)
{
  int tok  = blockIdx.x*4 + (threadIdx.x>>6);
  int lane = threadIdx.x & 63;
  const float* xr = x + (size_t)tok*D_MODEL;
  unsigned short* xb = xbf + (size_t)tok*D_MODEL;
  float acc0=0.f,acc1=0.f,acc2=0.f,acc3=0.f;
  #pragma unroll
  for (int j=0;j<4;j++){
    int k = lane*4 + j*256;
    f4 v  = *(const f4*)(xr + k);
    f4 w0 = *(const f4*)(Wgate + 0*D_MODEL + k);
    f4 w1 = *(const f4*)(Wgate + 1*D_MODEL + k);
    f4 w2 = *(const f4*)(Wgate + 2*D_MODEL + k);
    f4 w3 = *(const f4*)(Wgate + 3*D_MODEL + k);
    #pragma unroll
    for (int q=0;q<4;q++){
      acc0 += v[q]*w0[q];
      acc1 += v[q]*w1[q];
      acc2 += v[q]*w2[q];
      acc3 += v[q]*w3[q];
    }
    ushort4 o; o.x=f2b(v[0]); o.y=f2b(v[1]); o.z=f2b(v[2]); o.w=f2b(v[3]);
    *(ushort4*)(xb + k) = o;
  }
  #pragma unroll
  for (int off=32;off>0;off>>=1){
    acc0 += __shfl_down(acc0,off);
    acc1 += __shfl_down(acc1,off);
    acc2 += __shfl_down(acc2,off);
    acc3 += __shfl_down(acc3,off);
  }
  if (lane==0){
    float l[4]={acc0,acc1,acc2,acc3};
    int i1=0;
    #pragma unroll
    for(int e=1;e<4;e++) if (l[e]>l[i1]) i1=e;
    int i2=-1;
    #pragma unroll
    for(int e=0;e<4;e++){ if(e==i1) continue; if(i2<0||l[e]>l[i2]) i2=e; }
    float ex = __expf(l[i2]-l[i1]);
    float w1 = 1.f/(1.f+ex);
    float w2 = ex/(1.f+ex);
    float w[4]={0.f,0.f,0.f,0.f};
    w[i1]=w1; w[i2]=w2;
    float* wp = wtok + (size_t)tok*E_EXP;
    wp[0]=w[0]; wp[1]=w[1]; wp[2]=w[2]; wp[3]=w[3];
  }
}

// Wg/Wv/Wd expert slices -> Wcat[le][3][D][D] bf16
__global__ __launch_bounds__(256) void cvt_w3(const float* __restrict__ Wg,
                                              const float* __restrict__ Wv,
                                              const float* __restrict__ Wd,
                                              unsigned short* __restrict__ Wcat,
                                              int e0)
{
  const size_t DD = (size_t)D_MODEL*D_MODEL;   // 2^20
  size_t i4 = ((size_t)blockIdx.x*256 + threadIdx.x)*4;
  size_t le3m = i4 >> 20;          // / DD
  size_t rem  = i4 & (DD-1);
  int mat = (int)(le3m % 3);
  int le  = (int)(le3m / 3);
  const float* src = (mat==0 ? Wg : (mat==1 ? Wv : Wd)) + (size_t)(e0+le)*DD + rem;
  f4 v = *(const f4*)src;
  ushort4 o; o.x=f2b(v[0]); o.y=f2b(v[1]); o.z=f2b(v[2]); o.w=f2b(v[3]);
  *(ushort4*)(Wcat + le3m*DD + rem) = o;
}

// ---------------- 256x256 bf16 MFMA GEMM + T1 XCD swizzle + aa epilogue on d-mat ----
// Round-1/6 schedule (best measured). New: (a) bijective XCD block swizzle:
// each XCD gets a contiguous 192-block range = 3 weight mats (6MB, ~L2-resident);
// each 32-block generation shares ONE 2MB mat. (b) mat==2 epilogue applies
// aa = 0.001+0.998*sigmoid(d+bd) so pass1 need not rewrite the aa plane.
#define BM2 256
#define BN2 256
#define BK2 64
#define NT2 (D_MODEL/BK2)   // 16

__global__ __launch_bounds__(512, 2) void gemm256(
    const unsigned short* __restrict__ A,     // xbf [NTOK][D]
    const unsigned short* __restrict__ Wcat,  // [G][3][D][D] bf16
    unsigned short* __restrict__ gvd,         // [G][3][NTOK][D] bf16 (d-plane = aa)
    const float* __restrict__ bd, int e0)
{
  __shared__ unsigned short sA[2][BM2][BK2];  // 64 KiB
  __shared__ unsigned short sB[2][BN2][BK2];  // 64 KiB
  const size_t DD = (size_t)D_MODEL*D_MODEL;
  const size_t ND = (size_t)NTOK*D_MODEL;

  // T1 XCD-aware bijective swizzle (nwg = 768*G, divisible by 8)
  int orig = blockIdx.x + 64*(blockIdx.y + 12*blockIdx.z);
  int nwg  = 768*(int)gridDim.z;
  int nid  = (orig & 7)*(nwg>>3) + (orig>>3);
  int sx   = nid & 63;
  int qq   = nid >> 6;
  int sy   = qq % 12;
  int sz   = qq / 12;

  const int le    = sz;
  const int mbase = sx*BM2;
  const int ntile = sy;                      // 0..11
  const int mat   = ntile>>2;                // which matrix (g/v/d)
  const int nbase = (ntile&3)*BN2;           // col within matrix

  const int tid  = threadIdx.x;
  const int wave = tid>>6, lane = tid&63;
  const int wm = wave>>2, wn = wave&3;       // 2M x 4N wave grid; per-wave out 128x64
  const int l15 = lane&15;
  const int l8  = lane>>3;
  const int lc  = (lane&7) ^ l8;             // pre-swizzled logical chunk for staging

  const unsigned short* Wmat = Wcat + ((size_t)le*3 + mat)*DD;
  const unsigned short* gA = A + (size_t)(mbase + wave*8 + l8)*D_MODEL + lc*8;
  const int bBw = (wave>>1)*64 + (wave&1)*8; // per-wave B dest row base
  const unsigned short* gB = Wmat + (size_t)(nbase + bBw + l8)*D_MODEL + lc*8;

  // fragment read addressing (swizzle-aware)
  const int arow = wm*128 + l15;
  const int brow = wn*64  + l15;
  const int ach0 = (((lane>>4)    ) ^ (lane&7))*8;   // kk=0 phys chunk, ushort off
  const int ach1 = (((lane>>4) + 4) ^ (lane&7))*8;   // kk=1

  f32x4 acc[8][4];
  #pragma unroll
  for (int i=0;i<8;i++)
    #pragma unroll
    for (int j=0;j<4;j++) acc[i][j] = 0;

  bf16x8 af[4][2], bfv[2][2];

#define STAGE_A2(slot,t,mh) do{ \
  gload_lds16(gA + (size_t)((mh)*64)*D_MODEL     + (t)*BK2, &sA[slot][(mh)*64 + wave*8][0]); \
  gload_lds16(gA + (size_t)(128+(mh)*64)*D_MODEL + (t)*BK2, &sA[slot][128+(mh)*64 + wave*8][0]); \
}while(0)
#define STAGE_B2(slot,t,nh) do{ \
  gload_lds16(gB + (size_t)((nh)*32)*D_MODEL    + (t)*BK2, &sB[slot][bBw + (nh)*32][0]); \
  gload_lds16(gB + (size_t)((nh)*32+16)*D_MODEL + (t)*BK2, &sB[slot][bBw + (nh)*32 + 16][0]); \
}while(0)
#define LOAD_A2(slot,mh) do{ \
  _Pragma("unroll") for (int _m=0;_m<4;++_m){ \
    af[_m][0] = *(const bf16x8*)&sA[slot][arow + ((mh)*4+_m)*16][ach0]; \
    af[_m][1] = *(const bf16x8*)&sA[slot][arow + ((mh)*4+_m)*16][ach1]; \
  } \
}while(0)
#define LOAD_B2(slot,nh) do{ \
  _Pragma("unroll") for (int _n=0;_n<2;++_n){ \
    bfv[_n][0] = *(const bf16x8*)&sB[slot][brow + ((nh)*2+_n)*16][ach0]; \
    bfv[_n][1] = *(const bf16x8*)&sB[slot][brow + ((nh)*2+_n)*16][ach1]; \
  } \
}while(0)
#define MQ2(mh,nh) do{ \
  _Pragma("unroll") for (int _m=0;_m<4;++_m) \
  _Pragma("unroll") for (int _n=0;_n<2;++_n) \
  _Pragma("unroll") for (int _k=0;_k<2;++_k) \
    acc[(mh)*4+_m][(nh)*2+_n] = __builtin_amdgcn_mfma_f32_16x16x32_bf16( \
        af[_m][_k], bfv[_n][_k], acc[(mh)*4+_m][(nh)*2+_n], 0,0,0); \
}while(0)
#define KC_LGKM0  asm volatile("s_waitcnt lgkmcnt(0)" ::: "memory")
#define KC_LGKM8  asm volatile("s_waitcnt lgkmcnt(8)" ::: "memory")
#define KC_VM4    asm volatile("s_waitcnt vmcnt(4)" ::: "memory")
#define BAR       __builtin_amdgcn_s_barrier()
#define PRIO1     __builtin_amdgcn_s_setprio(1)
#define PRIO0     __builtin_amdgcn_s_setprio(0)

#define WINDOW2(slot,oslot,T1,T2) do{ \
  LOAD_A2(slot,0); LOAD_B2(slot,0); \
  STAGE_A2(oslot,T1,1); STAGE_B2(oslot,T1,0); \
  KC_LGKM8; BAR; KC_LGKM0; \
  PRIO1; MQ2(0,0); PRIO0; BAR; \
  LOAD_B2(slot,1); \
  BAR; KC_LGKM0; \
  PRIO1; MQ2(0,1); PRIO0; BAR; \
  LOAD_A2(slot,1); \
  STAGE_A2(slot,T2,0); \
  BAR; KC_LGKM0; \
  PRIO1; MQ2(1,1); PRIO0; BAR; \
  LOAD_B2(slot,0); \
  STAGE_B2(slot,T2,1); \
  KC_VM4; BAR; KC_LGKM0; \
  PRIO1; MQ2(1,0); PRIO0; BAR; \
}while(0)

  // prologue: tile 0 fully into slot0; A0+B1 of tile 1 into slot1 (left in flight)
  STAGE_A2(0,0,0); STAGE_A2(0,0,1); STAGE_B2(0,0,0); STAGE_B2(0,0,1);
  STAGE_A2(1,1,0); STAGE_B2(1,1,1);
  KC_VM4; BAR;

  for (int tp=0; tp<NT2/2; ++tp){
    int ta = 2*tp+1;                       // always < NT2
    int tb = 2*tp+2; if (tb>=NT2) tb -= NT2;   // wrapped stages are in-bounds junk
    int tc = 2*tp+3; if (tc>=NT2) tc -= NT2;
    WINDOW2(0,1,ta,tb);
    WINDOW2(1,0,tb,tc);
  }

  asm volatile("s_waitcnt vmcnt(0)" ::: "memory");   // drain tail junk stages before exit

  // epilogue: bf16 store (C/D layout col=lane&15, row=(lane>>4)*4+r).
  // mat==2: apply aa activation (block-uniform branch).
  unsigned short* outp = gvd + ((size_t)le*3 + mat)*ND;
  const int me = mbase + wm*128;
  const int ne = nbase + wn*64;
  if (mat == 2){
    float bdv[4];
    #pragma unroll
    for (int ni=0;ni<4;ni++) bdv[ni] = bd[(size_t)(e0+le)*D_MODEL + ne + ni*16 + l15];
    #pragma unroll
    for (int mi=0;mi<8;mi++){
      #pragma unroll
      for (int r=0;r<4;r++){
        int m = me + mi*16 + (lane>>4)*4 + r;
        size_t rowoff = (size_t)m*D_MODEL;
        #pragma unroll
        for (int ni=0;ni<4;ni++){
          int n = ne + ni*16 + l15;
          float aa = 0.001f + 0.998f/(1.f+__expf(-(acc[mi][ni][r]+bdv[ni])));
          outp[rowoff+n] = f2b(aa);
        }
      }
    }
  } else {
    #pragma unroll
    for (int mi=0;mi<8;mi++){
      #pragma unroll
      for (int r=0;r<4;r++){
        int m = me + mi*16 + (lane>>4)*4 + r;
        size_t rowoff = (size_t)m*D_MODEL;
        #pragma unroll
        for (int ni=0;ni<4;ni++){
          int n = ne + ni*16 + l15;
          outp[rowoff+n] = f2b(acc[mi][ni][r]);
        }
      }
    }
  }
}

// ---------------- pass 1: xs activation + local chunk scan; writes xs in place ----------------
// d-plane already holds activated aa (from gemm epilogue): read-only here.
__global__ __launch_bounds__(512) void scan_pass1(
    unsigned short* __restrict__ gvd,   // [G][3][NTOK][D]; g-plane becomes xs
    const float* __restrict__ bg, const float* __restrict__ bv,
    float* __restrict__ P, float* __restrict__ U, int e0)
{
  const size_t ND = (size_t)NTOK*D_MODEL;
  int blk = blockIdx.x;
  int c  = blk % NCHUNK;
  int b  = (blk / NCHUNK) % B_BATCH;
  int le = blk / (NCHUNK*B_BATCH);
  int d0 = threadIdx.x*2;
  int e  = e0 + le;

  float bg0 = bg[(size_t)e*D_MODEL+d0], bg1 = bg[(size_t)e*D_MODEL+d0+1];
  float bv0 = bv[(size_t)e*D_MODEL+d0], bv1 = bv[(size_t)e*D_MODEL+d0+1];

  unsigned short* gp = gvd + (size_t)le*3*ND;      // g plane (-> xs)
  size_t base = (((size_t)b)*S_SEQ + (size_t)c*CHUNK)*D_MODEL + d0;
  float h0=0.f,h1=0.f,p0=1.f,p1=1.f;
  for (int t=0;t<CHUNK;t++){
    unsigned gw = *(const unsigned*)(gp + base);
    unsigned vw = *(const unsigned*)(gp + ND + base);
    unsigned aw = *(const unsigned*)(gp + 2*ND + base);   // activated aa
    float g0 = b2f_lo(gw)+bg0, g1 = b2f_hi(gw)+bg1;
    float v0 = b2f_lo(vw)+bv0, v1 = b2f_hi(vw)+bv1;
    float a0 = b2f_lo(aw),     a1 = b2f_hi(aw);
    float x0 = (1.f/(1.f+__expf(-g0))) * (1.f - 2.f/(__expf(2.f*v0)+1.f));
    float x1 = (1.f/(1.f+__expf(-g1))) * (1.f - 2.f/(__expf(2.f*v1)+1.f));
    h0 = a0*h0 + x0; h1 = a1*h1 + x1;
    p0 *= a0; p1 *= a1;
    unsigned xsw = (unsigned)f2b(x0) | ((unsigned)f2b(x1)<<16);
    *(unsigned*)(gp + base) = xsw;   // xs over g-plane
    base += D_MODEL;
  }
  size_t sidx = (((size_t)(le*B_BATCH + b))*NCHUNK + c)*D_MODEL + d0;
  P[sidx]=p0; P[sidx+1]=p1;
  U[sidx]=h0; U[sidx+1]=h1;
}

// ---------------- pass 2: sequential combine over chunks -> Hinit per chunk ----------------
__global__ __launch_bounds__(256) void scan_pass2(
    const float* __restrict__ P, const float* __restrict__ U, float* __restrict__ Hinit)
{
  int ch = blockIdx.x*256 + threadIdx.x;
  int d  = ch & (D_MODEL-1);
  int eb = ch >> 10;
  size_t base = (size_t)eb*NCHUNK*D_MODEL + d;
  float H=0.f;
  for (int c=0;c<NCHUNK;c++){
    size_t idx = base + (size_t)c*D_MODEL;
    Hinit[idx] = H;
    H = P[idx]*H + U[idx];
  }
}

// ---------------- pass 3: re-scan + fused top-2 weighted combine ----------------
template<int G, int FIRST>
__global__ __launch_bounds__(512) void scan_pass3(
    const unsigned short* __restrict__ gvd,   // xs = plane le*3, aa = plane le*3+2
    const float* __restrict__ Hinit, const float* __restrict__ wtok,
    float* __restrict__ out, int e0)
{
  const size_t ND = (size_t)NTOK*D_MODEL;
  int blk = blockIdx.x;
  int c = blk % NCHUNK;
  int b = blk / NCHUNK;
  int d0 = threadIdx.x*2;
  float h[G][2];
  #pragma unroll
  for (int le=0; le<G; le++){
    size_t hi = (((size_t)(le*B_BATCH+b))*NCHUNK + c)*D_MODEL + d0;
    h[le][0]=Hinit[hi]; h[le][1]=Hinit[hi+1];
  }
  int s0 = c*CHUNK;
  for (int t=0;t<CHUNK;t++){
    size_t n = (size_t)b*S_SEQ + s0 + t;
    float o0=0.f, o1=0.f;
    #pragma unroll
    for (int le=0;le<G;le++){
      float w = wtok[n*E_EXP + e0 + le];
      size_t idx = (size_t)le*3*ND + n*D_MODEL + d0;
      unsigned xv = *(const unsigned*)(gvd + idx);
      unsigned av = *(const unsigned*)(gvd + 2*ND + idx);
      h[le][0] = b2f_lo(av)*h[le][0] + b2f_lo(xv);
      h[le][1] = b2f_hi(av)*h[le][1] + b2f_hi(xv);
      o0 += w*h[le][0];
      o1 += w*h[le][1];
    }
    float* op = out + n*D_MODEL + d0;
    if (FIRST){ op[0]=o0;  op[1]=o1;  }
    else      { op[0]+=o0; op[1]+=o1; }
  }
}

extern "C" void kernel_launch(void* const* d_in, const int* in_sizes, int n_in,
                              void* d_out, int out_size, void* d_ws, size_t ws_size,
                              hipStream_t stream)
{
  const float* x     = (const float*)d_in[0];
  const float* Wg    = (const float*)d_in[1];
  const float* bg    = (const float*)d_in[2];
  const float* Wv    = (const float*)d_in[3];
  const float* bv    = (const float*)d_in[4];
  const float* Wd    = (const float*)d_in[5];
  const float* bd    = (const float*)d_in[6];
  const float* Wgate = (const float*)d_in[7];
  float* out = (float*)d_out;

  const size_t DD        = (size_t)D_MODEL*D_MODEL;
  const size_t ND        = (size_t)NTOK*D_MODEL;
  const size_t wtok_b    = (size_t)NTOK*E_EXP*4;             // 256 KiB
  const size_t xbf_b     = ND*2;                             // 32 MiB
  const size_t w_per_e   = 3*DD*2;                           // 6 MiB
  const size_t gvd_per_e = 3*ND*2;                           // 96 MiB
  const size_t st_per_e  = (size_t)B_BATCH*NCHUNK*D_MODEL*4; // 2 MiB

  int G = 1;
  for (int g = 4; g >= 1; g >>= 1){
    size_t need = wtok_b + xbf_b + (size_t)g*(w_per_e + gvd_per_e + 3*st_per_e);
    if (need <= ws_size){ G = g; break; }
  }

  char* wsb = (char*)d_ws;
  size_t off = 0;
  float*          wtok = (float*)(wsb+off);          off += wtok_b;
  unsigned short* xbf  = (unsigned short*)(wsb+off); off += xbf_b;
  unsigned short* Wcat = (unsigned short*)(wsb+off); off += (size_t)G*w_per_e;
  unsigned short* gvd  = (unsigned short*)(wsb+off); off += (size_t)G*gvd_per_e;
  float*          P    = (float*)(wsb+off);          off += (size_t)G*st_per_e;
  float*          U    = (float*)(wsb+off);          off += (size_t)G*st_per_e;
  float*          Hi   = (float*)(wsb+off);

  prep<<<NTOK/4, 256, 0, stream>>>(x, Wgate, xbf, wtok);

  for (int e0=0; e0<E_EXP; e0+=G){
    cvt_w3<<<(unsigned)((size_t)G*3*DD/1024), 256, 0, stream>>>(Wg, Wv, Wd, Wcat, e0);

    dim3 gg(NTOK/BM2, 3*D_MODEL/BN2, G);
    gemm256<<<gg, 512, 0, stream>>>(xbf, Wcat, gvd, bd, e0);

    scan_pass1<<<G*B_BATCH*NCHUNK, 512, 0, stream>>>(gvd, bg, bv, P, U, e0);
    scan_pass2<<<G*B_BATCH*D_MODEL/256, 256, 0, stream>>>(P, U, Hi);
    bool first = (e0 == 0);
    if (G==4)      scan_pass3<4,1><<<B_BATCH*NCHUNK, 512, 0, stream>>>(gvd, Hi, wtok, out, e0);
    else if (G==2){
      if (first) scan_pass3<2,1><<<B_BATCH*NCHUNK, 512, 0, stream>>>(gvd, Hi, wtok, out, e0);
      else       scan_pass3<2,0><<<B_BATCH*NCHUNK, 512, 0, stream>>>(gvd, Hi, wtok, out, e0);
    } else {
      if (first) scan_pass3<1,1><<<B_BATCH*NCHUNK, 512, 0, stream>>>(gvd, Hi, wtok, out, e0);
      else       scan_pass3<1,0><<<B_BATCH*NCHUNK, 512, 0, stream>>>(gvd, Hi, wtok, out, e0);
    }
  }
}

// Round 10
// 784.926 us; speedup vs baseline: 1.1723x; 1.0804x over previous
//
#include <hip/hip_runtime.h>

#define E_EXP 4
#define D_MODEL 1024
#define B_BATCH 4
#define S_SEQ 4096
#define NTOK (B_BATCH*S_SEQ)   // 16384
#define CHUNK 32
#define NCHUNK (S_SEQ/CHUNK)   // 128

typedef float f4 __attribute__((ext_vector_type(4)));
typedef float f32x4 __attribute__((ext_vector_type(4)));
typedef short bf16x8 __attribute__((ext_vector_type(8)));

__device__ __forceinline__ unsigned short f2b(float f){
  union{float f;unsigned u;}v; v.f=f;
  unsigned r = v.u + 0x7fffu + ((v.u>>16)&1u);
  return (unsigned short)(r>>16);
}
__device__ __forceinline__ float b2f_lo(unsigned v){ union{unsigned u;float f;}x; x.u=v<<16; return x.f; }
__device__ __forceinline__ float b2f_hi(unsigned v){ union{unsigned u;float f;}x; x.u=v&0xffff0000u; return x.f; }

__device__ __forceinline__ void gload_lds16(const void* g, void* l){
  __builtin_amdgcn_global_load_lds(
      (const __attribute__((address_space(1))) void*)g,
      (__attribute__((address_space(3))) void*)l, 16, 0, 0);
}

// ---------------- fused prep: x -> bf16 AND router top-2 softmax (reads x ONCE) ----
__global__ __launch_bounds__(256) void prep(
    const float* __restrict__ x, const float* __restrict__ Wgate,
    unsigned short* __restrict__ xbf, float* __restrict__ wtok)
{
  int tok  = blockIdx.x*4 + (threadIdx.x>>6);
  int lane = threadIdx.x & 63;
  const float* xr = x + (size_t)tok*D_MODEL;
  unsigned short* xb = xbf + (size_t)tok*D_MODEL;
  float acc0=0.f,acc1=0.f,acc2=0.f,acc3=0.f;
  #pragma unroll
  for (int j=0;j<4;j++){
    int k = lane*4 + j*256;
    f4 v  = *(const f4*)(xr + k);
    f4 w0 = *(const f4*)(Wgate + 0*D_MODEL + k);
    f4 w1 = *(const f4*)(Wgate + 1*D_MODEL + k);
    f4 w2 = *(const f4*)(Wgate + 2*D_MODEL + k);
    f4 w3 = *(const f4*)(Wgate + 3*D_MODEL + k);
    #pragma unroll
    for (int q=0;q<4;q++){
      acc0 += v[q]*w0[q];
      acc1 += v[q]*w1[q];
      acc2 += v[q]*w2[q];
      acc3 += v[q]*w3[q];
    }
    ushort4 o; o.x=f2b(v[0]); o.y=f2b(v[1]); o.z=f2b(v[2]); o.w=f2b(v[3]);
    *(ushort4*)(xb + k) = o;
  }
  #pragma unroll
  for (int off=32;off>0;off>>=1){
    acc0 += __shfl_down(acc0,off);
    acc1 += __shfl_down(acc1,off);
    acc2 += __shfl_down(acc2,off);
    acc3 += __shfl_down(acc3,off);
  }
  if (lane==0){
    float l[4]={acc0,acc1,acc2,acc3};
    int i1=0;
    #pragma unroll
    for(int e=1;e<4;e++) if (l[e]>l[i1]) i1=e;
    int i2=-1;
    #pragma unroll
    for(int e=0;e<4;e++){ if(e==i1) continue; if(i2<0||l[e]>l[i2]) i2=e; }
    float ex = __expf(l[i2]-l[i1]);
    float w1 = 1.f/(1.f+ex);
    float w2 = ex/(1.f+ex);
    float w[4]={0.f,0.f,0.f,0.f};
    w[i1]=w1; w[i2]=w2;
    float* wp = wtok + (size_t)tok*E_EXP;
    wp[0]=w[0]; wp[1]=w[1]; wp[2]=w[2]; wp[3]=w[3];
  }
}

// Wg/Wv/Wd expert slices -> Wcat[le][3][D][D] bf16
__global__ __launch_bounds__(256) void cvt_w3(const float* __restrict__ Wg,
                                              const float* __restrict__ Wv,
                                              const float* __restrict__ Wd,
                                              unsigned short* __restrict__ Wcat,
                                              int e0)
{
  const size_t DD = (size_t)D_MODEL*D_MODEL;   // 2^20
  size_t i4 = ((size_t)blockIdx.x*256 + threadIdx.x)*4;
  size_t le3m = i4 >> 20;          // / DD
  size_t rem  = i4 & (DD-1);
  int mat = (int)(le3m % 3);
  int le  = (int)(le3m / 3);
  const float* src = (mat==0 ? Wg : (mat==1 ? Wv : Wd)) + (size_t)(e0+le)*DD + rem;
  f4 v = *(const f4*)src;
  ushort4 o; o.x=f2b(v[0]); o.y=f2b(v[1]); o.z=f2b(v[2]); o.w=f2b(v[3]);
  *(ushort4*)(Wcat + le3m*DD + rem) = o;
}

// ---------------- 256x256 bf16 MFMA GEMM + aa epilogue on d-mat ----------------
// Round-1/6 schedule + DEFAULT block mapping (round-9 lesson: XCD swizzle
// de-synchronizes the chip-wide lockstep A sweep that lets L3 serve A re-reads;
// FETCH went 164->443 MB. Default x-fastest dispatch IS the right mapping here).
// mat==2 epilogue applies aa = 0.001+0.998*sigmoid(d+bd) (round-9 verified win:
// pass1 no longer computes/writes the aa plane, -84 us scan-side).
#define BM2 256
#define BN2 256
#define BK2 64
#define NT2 (D_MODEL/BK2)   // 16

__global__ __launch_bounds__(512, 2) void gemm256(
    const unsigned short* __restrict__ A,     // xbf [NTOK][D]
    const unsigned short* __restrict__ Wcat,  // [G][3][D][D] bf16
    unsigned short* __restrict__ gvd,         // [G][3][NTOK][D] bf16 (d-plane = aa)
    const float* __restrict__ bd, int e0)
{
  __shared__ unsigned short sA[2][BM2][BK2];  // 64 KiB
  __shared__ unsigned short sB[2][BN2][BK2];  // 64 KiB
  const size_t DD = (size_t)D_MODEL*D_MODEL;
  const size_t ND = (size_t)NTOK*D_MODEL;

  const int le    = blockIdx.z;
  const int mbase = blockIdx.x*BM2;
  const int ntile = blockIdx.y;              // 0..11
  const int mat   = ntile>>2;                // which matrix (g/v/d)
  const int nbase = (ntile&3)*BN2;           // col within matrix

  const int tid  = threadIdx.x;
  const int wave = tid>>6, lane = tid&63;
  const int wm = wave>>2, wn = wave&3;       // 2M x 4N wave grid; per-wave out 128x64
  const int l15 = lane&15;
  const int l8  = lane>>3;
  const int lc  = (lane&7) ^ l8;             // pre-swizzled logical chunk for staging

  const unsigned short* Wmat = Wcat + ((size_t)le*3 + mat)*DD;
  const unsigned short* gA = A + (size_t)(mbase + wave*8 + l8)*D_MODEL + lc*8;
  const int bBw = (wave>>1)*64 + (wave&1)*8; // per-wave B dest row base
  const unsigned short* gB = Wmat + (size_t)(nbase + bBw + l8)*D_MODEL + lc*8;

  // fragment read addressing (swizzle-aware)
  const int arow = wm*128 + l15;
  const int brow = wn*64  + l15;
  const int ach0 = (((lane>>4)    ) ^ (lane&7))*8;   // kk=0 phys chunk, ushort off
  const int ach1 = (((lane>>4) + 4) ^ (lane&7))*8;   // kk=1

  f32x4 acc[8][4];
  #pragma unroll
  for (int i=0;i<8;i++)
    #pragma unroll
    for (int j=0;j<4;j++) acc[i][j] = 0;

  bf16x8 af[4][2], bfv[2][2];

#define STAGE_A2(slot,t,mh) do{ \
  gload_lds16(gA + (size_t)((mh)*64)*D_MODEL     + (t)*BK2, &sA[slot][(mh)*64 + wave*8][0]); \
  gload_lds16(gA + (size_t)(128+(mh)*64)*D_MODEL + (t)*BK2, &sA[slot][128+(mh)*64 + wave*8][0]); \
}while(0)
#define STAGE_B2(slot,t,nh) do{ \
  gload_lds16(gB + (size_t)((nh)*32)*D_MODEL    + (t)*BK2, &sB[slot][bBw + (nh)*32][0]); \
  gload_lds16(gB + (size_t)((nh)*32+16)*D_MODEL + (t)*BK2, &sB[slot][bBw + (nh)*32 + 16][0]); \
}while(0)
#define LOAD_A2(slot,mh) do{ \
  _Pragma("unroll") for (int _m=0;_m<4;++_m){ \
    af[_m][0] = *(const bf16x8*)&sA[slot][arow + ((mh)*4+_m)*16][ach0]; \
    af[_m][1] = *(const bf16x8*)&sA[slot][arow + ((mh)*4+_m)*16][ach1]; \
  } \
}while(0)
#define LOAD_B2(slot,nh) do{ \
  _Pragma("unroll") for (int _n=0;_n<2;++_n){ \
    bfv[_n][0] = *(const bf16x8*)&sB[slot][brow + ((nh)*2+_n)*16][ach0]; \
    bfv[_n][1] = *(const bf16x8*)&sB[slot][brow + ((nh)*2+_n)*16][ach1]; \
  } \
}while(0)
#define MQ2(mh,nh) do{ \
  _Pragma("unroll") for (int _m=0;_m<4;++_m) \
  _Pragma("unroll") for (int _n=0;_n<2;++_n) \
  _Pragma("unroll") for (int _k=0;_k<2;++_k) \
    acc[(mh)*4+_m][(nh)*2+_n] = __builtin_amdgcn_mfma_f32_16x16x32_bf16( \
        af[_m][_k], bfv[_n][_k], acc[(mh)*4+_m][(nh)*2+_n], 0,0,0); \
}while(0)
#define KC_LGKM0  asm volatile("s_waitcnt lgkmcnt(0)" ::: "memory")
#define KC_LGKM8  asm volatile("s_waitcnt lgkmcnt(8)" ::: "memory")
#define KC_VM4    asm volatile("s_waitcnt vmcnt(4)" ::: "memory")
#define BAR       __builtin_amdgcn_s_barrier()
#define PRIO1     __builtin_amdgcn_s_setprio(1)
#define PRIO0     __builtin_amdgcn_s_setprio(0)

#define WINDOW2(slot,oslot,T1,T2) do{ \
  LOAD_A2(slot,0); LOAD_B2(slot,0); \
  STAGE_A2(oslot,T1,1); STAGE_B2(oslot,T1,0); \
  KC_LGKM8; BAR; KC_LGKM0; \
  PRIO1; MQ2(0,0); PRIO0; BAR; \
  LOAD_B2(slot,1); \
  BAR; KC_LGKM0; \
  PRIO1; MQ2(0,1); PRIO0; BAR; \
  LOAD_A2(slot,1); \
  STAGE_A2(slot,T2,0); \
  BAR; KC_LGKM0; \
  PRIO1; MQ2(1,1); PRIO0; BAR; \
  LOAD_B2(slot,0); \
  STAGE_B2(slot,T2,1); \
  KC_VM4; BAR; KC_LGKM0; \
  PRIO1; MQ2(1,0); PRIO0; BAR; \
}while(0)

  // prologue: tile 0 fully into slot0; A0+B1 of tile 1 into slot1 (left in flight)
  STAGE_A2(0,0,0); STAGE_A2(0,0,1); STAGE_B2(0,0,0); STAGE_B2(0,0,1);
  STAGE_A2(1,1,0); STAGE_B2(1,1,1);
  KC_VM4; BAR;

  for (int tp=0; tp<NT2/2; ++tp){
    int ta = 2*tp+1;                       // always < NT2
    int tb = 2*tp+2; if (tb>=NT2) tb -= NT2;   // wrapped stages are in-bounds junk
    int tc = 2*tp+3; if (tc>=NT2) tc -= NT2;
    WINDOW2(0,1,ta,tb);
    WINDOW2(1,0,tb,tc);
  }

  asm volatile("s_waitcnt vmcnt(0)" ::: "memory");   // drain tail junk stages before exit

  // epilogue: bf16 store (C/D layout col=lane&15, row=(lane>>4)*4+r).
  // mat==2: apply aa activation (block-uniform branch).
  unsigned short* outp = gvd + ((size_t)le*3 + mat)*ND;
  const int me = mbase + wm*128;
  const int ne = nbase + wn*64;
  if (mat == 2){
    float bdv[4];
    #pragma unroll
    for (int ni=0;ni<4;ni++) bdv[ni] = bd[(size_t)(e0+le)*D_MODEL + ne + ni*16 + l15];
    #pragma unroll
    for (int mi=0;mi<8;mi++){
      #pragma unroll
      for (int r=0;r<4;r++){
        int m = me + mi*16 + (lane>>4)*4 + r;
        size_t rowoff = (size_t)m*D_MODEL;
        #pragma unroll
        for (int ni=0;ni<4;ni++){
          int n = ne + ni*16 + l15;
          float aa = 0.001f + 0.998f/(1.f+__expf(-(acc[mi][ni][r]+bdv[ni])));
          outp[rowoff+n] = f2b(aa);
        }
      }
    }
  } else {
    #pragma unroll
    for (int mi=0;mi<8;mi++){
      #pragma unroll
      for (int r=0;r<4;r++){
        int m = me + mi*16 + (lane>>4)*4 + r;
        size_t rowoff = (size_t)m*D_MODEL;
        #pragma unroll
        for (int ni=0;ni<4;ni++){
          int n = ne + ni*16 + l15;
          outp[rowoff+n] = f2b(acc[mi][ni][r]);
        }
      }
    }
  }
}

// ---------------- pass 1: xs activation + local chunk scan; writes xs in place ----------------
// d-plane already holds activated aa (from gemm epilogue): read-only here.
__global__ __launch_bounds__(512) void scan_pass1(
    unsigned short* __restrict__ gvd,   // [G][3][NTOK][D]; g-plane becomes xs
    const float* __restrict__ bg, const float* __restrict__ bv,
    float* __restrict__ P, float* __restrict__ U, int e0)
{
  const size_t ND = (size_t)NTOK*D_MODEL;
  int blk = blockIdx.x;
  int c  = blk % NCHUNK;
  int b  = (blk / NCHUNK) % B_BATCH;
  int le = blk / (NCHUNK*B_BATCH);
  int d0 = threadIdx.x*2;
  int e  = e0 + le;

  float bg0 = bg[(size_t)e*D_MODEL+d0], bg1 = bg[(size_t)e*D_MODEL+d0+1];
  float bv0 = bv[(size_t)e*D_MODEL+d0], bv1 = bv[(size_t)e*D_MODEL+d0+1];

  unsigned short* gp = gvd + (size_t)le*3*ND;      // g plane (-> xs)
  size_t base = (((size_t)b)*S_SEQ + (size_t)c*CHUNK)*D_MODEL + d0;
  float h0=0.f,h1=0.f,p0=1.f,p1=1.f;
  for (int t=0;t<CHUNK;t++){
    unsigned gw = *(const unsigned*)(gp + base);
    unsigned vw = *(const unsigned*)(gp + ND + base);
    unsigned aw = *(const unsigned*)(gp + 2*ND + base);   // activated aa
    float g0 = b2f_lo(gw)+bg0, g1 = b2f_hi(gw)+bg1;
    float v0 = b2f_lo(vw)+bv0, v1 = b2f_hi(vw)+bv1;
    float a0 = b2f_lo(aw),     a1 = b2f_hi(aw);
    float x0 = (1.f/(1.f+__expf(-g0))) * (1.f - 2.f/(__expf(2.f*v0)+1.f));
    float x1 = (1.f/(1.f+__expf(-g1))) * (1.f - 2.f/(__expf(2.f*v1)+1.f));
    h0 = a0*h0 + x0; h1 = a1*h1 + x1;
    p0 *= a0; p1 *= a1;
    unsigned xsw = (unsigned)f2b(x0) | ((unsigned)f2b(x1)<<16);
    *(unsigned*)(gp + base) = xsw;   // xs over g-plane
    base += D_MODEL;
  }
  size_t sidx = (((size_t)(le*B_BATCH + b))*NCHUNK + c)*D_MODEL + d0;
  P[sidx]=p0; P[sidx+1]=p1;
  U[sidx]=h0; U[sidx+1]=h1;
}

// ---------------- pass 2: sequential combine over chunks -> Hinit per chunk ----------------
__global__ __launch_bounds__(256) void scan_pass2(
    const float* __restrict__ P, const float* __restrict__ U, float* __restrict__ Hinit)
{
  int ch = blockIdx.x*256 + threadIdx.x;
  int d  = ch & (D_MODEL-1);
  int eb = ch >> 10;
  size_t base = (size_t)eb*NCHUNK*D_MODEL + d;
  float H=0.f;
  for (int c=0;c<NCHUNK;c++){
    size_t idx = base + (size_t)c*D_MODEL;
    Hinit[idx] = H;
    H = P[idx]*H + U[idx];
  }
}

// ---------------- pass 3: re-scan + fused top-2 weighted combine ----------------
template<int G, int FIRST>
__global__ __launch_bounds__(512) void scan_pass3(
    const unsigned short* __restrict__ gvd,   // xs = plane le*3, aa = plane le*3+2
    const float* __restrict__ Hinit, const float* __restrict__ wtok,
    float* __restrict__ out, int e0)
{
  const size_t ND = (size_t)NTOK*D_MODEL;
  int blk = blockIdx.x;
  int c = blk % NCHUNK;
  int b = blk / NCHUNK;
  int d0 = threadIdx.x*2;
  float h[G][2];
  #pragma unroll
  for (int le=0; le<G; le++){
    size_t hi = (((size_t)(le*B_BATCH+b))*NCHUNK + c)*D_MODEL + d0;
    h[le][0]=Hinit[hi]; h[le][1]=Hinit[hi+1];
  }
  int s0 = c*CHUNK;
  for (int t=0;t<CHUNK;t++){
    size_t n = (size_t)b*S_SEQ + s0 + t;
    float o0=0.f, o1=0.f;
    #pragma unroll
    for (int le=0;le<G;le++){
      float w = wtok[n*E_EXP + e0 + le];
      size_t idx = (size_t)le*3*ND + n*D_MODEL + d0;
      unsigned xv = *(const unsigned*)(gvd + idx);
      unsigned av = *(const unsigned*)(gvd + 2*ND + idx);
      h[le][0] = b2f_lo(av)*h[le][0] + b2f_lo(xv);
      h[le][1] = b2f_hi(av)*h[le][1] + b2f_hi(xv);
      o0 += w*h[le][0];
      o1 += w*h[le][1];
    }
    float* op = out + n*D_MODEL + d0;
    if (FIRST){ op[0]=o0;  op[1]=o1;  }
    else      { op[0]+=o0; op[1]+=o1; }
  }
}

extern "C" void kernel_launch(void* const* d_in, const int* in_sizes, int n_in,
                              void* d_out, int out_size, void* d_ws, size_t ws_size,
                              hipStream_t stream)
{
  const float* x     = (const float*)d_in[0];
  const float* Wg    = (const float*)d_in[1];
  const float* bg    = (const float*)d_in[2];
  const float* Wv    = (const float*)d_in[3];
  const float* bv    = (const float*)d_in[4];
  const float* Wd    = (const float*)d_in[5];
  const float* bd    = (const float*)d_in[6];
  const float* Wgate = (const float*)d_in[7];
  float* out = (float*)d_out;

  const size_t DD        = (size_t)D_MODEL*D_MODEL;
  const size_t ND        = (size_t)NTOK*D_MODEL;
  const size_t wtok_b    = (size_t)NTOK*E_EXP*4;             // 256 KiB
  const size_t xbf_b     = ND*2;                             // 32 MiB
  const size_t w_per_e   = 3*DD*2;                           // 6 MiB
  const size_t gvd_per_e = 3*ND*2;                           // 96 MiB
  const size_t st_per_e  = (size_t)B_BATCH*NCHUNK*D_MODEL*4; // 2 MiB

  int G = 1;
  for (int g = 4; g >= 1; g >>= 1){
    size_t need = wtok_b + xbf_b + (size_t)g*(w_per_e + gvd_per_e + 3*st_per_e);
    if (need <= ws_size){ G = g; break; }
  }

  char* wsb = (char*)d_ws;
  size_t off = 0;
  float*          wtok = (float*)(wsb+off);          off += wtok_b;
  unsigned short* xbf  = (unsigned short*)(wsb+off); off += xbf_b;
  unsigned short* Wcat = (unsigned short*)(wsb+off); off += (size_t)G*w_per_e;
  unsigned short* gvd  = (unsigned short*)(wsb+off); off += (size_t)G*gvd_per_e;
  float*          P    = (float*)(wsb+off);          off += (size_t)G*st_per_e;
  float*          U    = (float*)(wsb+off);          off += (size_t)G*st_per_e;
  float*          Hi   = (float*)(wsb+off);

  prep<<<NTOK/4, 256, 0, stream>>>(x, Wgate, xbf, wtok);

  for (int e0=0; e0<E_EXP; e0+=G){
    cvt_w3<<<(unsigned)((size_t)G*3*DD/1024), 256, 0, stream>>>(Wg, Wv, Wd, Wcat, e0);

    dim3 gg(NTOK/BM2, 3*D_MODEL/BN2, G);
    gemm256<<<gg, 512, 0, stream>>>(xbf, Wcat, gvd, bd, e0);

    scan_pass1<<<G*B_BATCH*NCHUNK, 512, 0, stream>>>(gvd, bg, bv, P, U, e0);
    scan_pass2<<<G*B_BATCH*D_MODEL/256, 256, 0, stream>>>(P, U, Hi);
    bool first = (e0 == 0);
    if (G==4)      scan_pass3<4,1><<<B_BATCH*NCHUNK, 512, 0, stream>>>(gvd, Hi, wtok, out, e0);
    else if (G==2){
      if (first) scan_pass3<2,1><<<B_BATCH*NCHUNK, 512, 0, stream>>>(gvd, Hi, wtok, out, e0);
      else       scan_pass3<2,0><<<B_BATCH*NCHUNK, 512, 0, stream>>>(gvd, Hi, wtok, out, e0);
    } else {
      if (first) scan_pass3<1,1><<<B_BATCH*NCHUNK, 512, 0, stream>>>(gvd, Hi, wtok, out, e0);
      else       scan_pass3<1,0><<<B_BATCH*NCHUNK, 512, 0, stream>>>(gvd, Hi, wtok, out, e0);
    }
  }
}